// Round 3
// baseline (8961.132 us; speedup 1.0000x reference)
//
#include <hip/hip_runtime.h>

// FAVOR+ attention, B=4 L=4096 D=1024 H=16 d=64 m=256.
// Reference setup_inputs is float32; harness MAY serve a bf16-converted
// variant. A detector kernel classifies the buffer dtype at runtime and the
// matching templated path runs (the other exits immediately).
// stab = 0 (global stabilizer cancels between numerator/denominator; only
// rescales eps by e^stab — ~1e-6 output effect).
// K1 per (b,h, m-chunk): k' = m^-0.5(exp(-0.5||k^||^2 + k^.W_m)+eps),
//    accumulate ksum[m], kv[m][d] (fp32 in ws).
// K2 per (b,h, 64-row L-tile): q' = m^-0.5(exp(q^.W_m)+eps),
//    denom = q'.ksum, out = (q'@kv)/denom.

typedef unsigned short u16;
typedef __attribute__((ext_vector_type(8))) unsigned short ushort8;

#define NB 4
#define NL 4096
#define ND 1024
#define NH 16
#define HDIM 64
#define NM 256

#define SCALE 0.17677669529663687f  // 1024^-0.25
#define RSQM 0.0625f                // 256^-0.5
#define FEPS 1e-4f
#define ECLAMP 80.0f                // inert for sane data; bars inf

__device__ __forceinline__ float bf2f(u16 u) {
  union { unsigned int i; float f; } x;
  x.i = ((unsigned int)u) << 16;
  return x.f;
}
__device__ __forceinline__ u16 f2bf(float f) {
  union { float f; unsigned int i; } x;
  x.f = f;
  unsigned int i = x.i;
  i += 0x7fffu + ((i >> 16) & 1u);  // round-to-nearest-even
  return (u16)(i >> 16);
}

// MODE 1 = fp32 buffers, MODE 0 = bf16 buffers. off in elements (multiple of 8).
template <int MODE>
__device__ __forceinline__ void load8(const void* base, size_t off, float* o) {
  if (MODE == 1) {
    const float* p = (const float*)base + off;
    float4 a = *(const float4*)p;
    float4 b = *(const float4*)(p + 4);
    o[0] = a.x; o[1] = a.y; o[2] = a.z; o[3] = a.w;
    o[4] = b.x; o[5] = b.y; o[6] = b.z; o[7] = b.w;
  } else {
    ushort8 u = *(const ushort8*)((const u16*)base + off);
#pragma unroll
    for (int j = 0; j < 8; j++) o[j] = bf2f(u[j]);
  }
}

// True bf16 gaussian data: exponent fields in ~[113,130]. fp32 data viewed as
// ushorts: half are mantissa halves with uniform exponents -> many outliers.
__global__ void detect_kernel(const u16* __restrict__ q, int* __restrict__ flag) {
  __shared__ int cnt;
  if (threadIdx.x == 0) cnt = 0;
  __syncthreads();
  u16 u = q[threadIdx.x];
  int e = (u >> 7) & 0xff;
  if (e < 100 || e > 140) atomicAdd(&cnt, 1);
  __syncthreads();
  if (threadIdx.x == 0) flag[0] = (cnt > 16) ? 1 : 0;
}

// Grid: 64 (b,h) x 4 m-chunks = 256 blocks, 512 threads.
// Thread = (m_local 0..63, row-group 0..7). W row + kv[64] in registers.
template <int MODE>
__global__ __launch_bounds__(512) void kv_kernel(const void* __restrict__ kptr,
                                                 const void* __restrict__ vptr,
                                                 const void* __restrict__ wptr,
                                                 const int* __restrict__ flagp,
                                                 float* __restrict__ kvg,
                                                 float* __restrict__ ksumg) {
  if (flagp[0] != MODE) return;
  const int bh = blockIdx.x >> 2;
  const int mc = blockIdx.x & 3;
  const int b = bh >> 4, h = bh & 15;
  const int tid = threadIdx.x;
  const int ml = tid & 63;
  const int lq = tid >> 6;
  const int m = mc * 64 + ml;

  __shared__ __align__(16) float Kl[64][68];
  __shared__ __align__(16) float Vl[64][68];
  __shared__ float cl[64];
  __shared__ float accs[64][65];
  __shared__ float ksl[64];

  float Wreg[64];
#pragma unroll
  for (int c = 0; c < 8; c++) load8<MODE>(wptr, (size_t)m * 64 + c * 8, &Wreg[c * 8]);

  float kvacc[64];
#pragma unroll
  for (int j = 0; j < 64; j++) kvacc[j] = 0.f;
  float ksacc = 0.f;

  const size_t base = (size_t)b * NL * ND + (size_t)h * 64;
  const int srow = tid >> 3;  // staging: 512 threads x 8 elems = 64x64 tile
  const int sj = (tid & 7) * 8;
  for (int t = 0; t < 64; t++) {
    __syncthreads();  // protect LDS reuse from previous iteration's readers
    float kv8[8], vv8[8];
    load8<MODE>(kptr, base + (size_t)t * 64 * ND + (size_t)srow * ND + sj, kv8);
    load8<MODE>(vptr, base + (size_t)t * 64 * ND + (size_t)srow * ND + sj, vv8);
#pragma unroll
    for (int j = 0; j < 8; j++) {
      Kl[srow][sj + j] = kv8[j] * SCALE;
      Vl[srow][sj + j] = vv8[j];
    }
    __syncthreads();
    if (tid < 64) {  // h_l per row (stab = 0)
      const float4* kr = (const float4*)(&Kl[tid][0]);
      float s = 0.f;
#pragma unroll
      for (int c = 0; c < 16; c++) {
        float4 kq = kr[c];
        s = fmaf(kq.x, kq.x, s); s = fmaf(kq.y, kq.y, s);
        s = fmaf(kq.z, kq.z, s); s = fmaf(kq.w, kq.w, s);
      }
      cl[tid] = -0.5f * s;
    }
    __syncthreads();
    for (int i = 0; i < 8; i++) {
      const int l = lq * 8 + i;
      const float4* kr = (const float4*)(&Kl[l][0]);
      const float4* vr = (const float4*)(&Vl[l][0]);
      float p0 = 0.f, p1 = 0.f, p2 = 0.f, p3 = 0.f;
#pragma unroll
      for (int c = 0; c < 16; c++) {
        float4 kq = kr[c];
        p0 = fmaf(kq.x, Wreg[4 * c + 0], p0);
        p1 = fmaf(kq.y, Wreg[4 * c + 1], p1);
        p2 = fmaf(kq.z, Wreg[4 * c + 2], p2);
        p3 = fmaf(kq.w, Wreg[4 * c + 3], p3);
      }
      const float arg = fminf(cl[l] + ((p0 + p1) + (p2 + p3)), ECLAMP);
      const float kpv = RSQM * __expf(arg) + (RSQM * FEPS);
      ksacc += kpv;
#pragma unroll
      for (int c = 0; c < 16; c++) {
        float4 vv = vr[c];
        kvacc[4 * c + 0] = fmaf(kpv, vv.x, kvacc[4 * c + 0]);
        kvacc[4 * c + 1] = fmaf(kpv, vv.y, kvacc[4 * c + 1]);
        kvacc[4 * c + 2] = fmaf(kpv, vv.z, kvacc[4 * c + 2]);
        kvacc[4 * c + 3] = fmaf(kpv, vv.w, kvacc[4 * c + 3]);
      }
    }
  }
  // serial reduce across the 8 row-groups (deterministic order)
  for (int g = 0; g < 8; g++) {
    if (lq == g) {
      if (g == 0) {
#pragma unroll
        for (int j = 0; j < 64; j++) accs[ml][j] = kvacc[j];
        ksl[ml] = ksacc;
      } else {
#pragma unroll
        for (int j = 0; j < 64; j++) accs[ml][j] += kvacc[j];
        ksl[ml] += ksacc;
      }
    }
    __syncthreads();
  }
  float* kvout = kvg + ((size_t)bh * NM + mc * 64) * HDIM;
  for (int e = tid; e < 64 * 64; e += 512) kvout[e] = accs[e >> 6][e & 63];
  if (tid < 64) ksumg[(size_t)bh * NM + mc * 64 + tid] = ksl[tid];
}

// Grid: 64 (b,h) x 64 L-tiles (64 rows) = 4096 blocks, 512 threads.
template <int MODE>
__global__ __launch_bounds__(512) void out_kernel(const void* __restrict__ qptr,
                                                  const void* __restrict__ wptr,
                                                  const float* __restrict__ kvg,
                                                  const float* __restrict__ ksumg,
                                                  const int* __restrict__ flagp,
                                                  void* __restrict__ outp) {
  if (flagp[0] != MODE) return;
  const int bh = blockIdx.x >> 6;
  const int t = blockIdx.x & 63;
  const int b = bh >> 4, h = bh & 15;
  const int tid = threadIdx.x;
  const int mth = tid & 255;
  const int hf = tid >> 8;
  const int dj = tid & 63;
  const int mg = tid >> 6;

  __shared__ __align__(16) float qp[32][260];
  __shared__ float accs[32][64];
  __shared__ float ksl[256];
  __shared__ float dpart[32][4];
  __shared__ float dinv[32];

  float Wreg[64];
#pragma unroll
  for (int c = 0; c < 8; c++) load8<MODE>(wptr, (size_t)mth * 64 + c * 8, &Wreg[c * 8]);

  float kvreg[32];
  {
    const float* kvb = kvg + (size_t)bh * NM * HDIM;
#pragma unroll
    for (int i = 0; i < 32; i++) kvreg[i] = kvb[(mg * 32 + i) * 64 + dj];
  }
  if (tid < 256) ksl[tid] = ksumg[(size_t)bh * NM + tid];
  __syncthreads();

  const size_t tbase = (size_t)b * NL * ND + (size_t)h * 64 + (size_t)t * 64 * ND;

  for (int s = 0; s < 2; s++) {
    // phase 1: q' for rows s*32 .. s*32+31 (each row read by 256 lanes -> L1 broadcast)
    for (int i = 0; i < 16; i++) {
      const int lr = hf * 16 + i;
      const int l = s * 32 + lr;
      float p0 = 0.f, p1 = 0.f, p2 = 0.f, p3 = 0.f;
#pragma unroll
      for (int c = 0; c < 8; c++) {
        float qv[8];
        load8<MODE>(qptr, tbase + (size_t)l * ND + c * 8, qv);
        p0 = fmaf(qv[0] * SCALE, Wreg[c * 8 + 0], p0);
        p1 = fmaf(qv[1] * SCALE, Wreg[c * 8 + 1], p1);
        p2 = fmaf(qv[2] * SCALE, Wreg[c * 8 + 2], p2);
        p3 = fmaf(qv[3] * SCALE, Wreg[c * 8 + 3], p3);
        p0 = fmaf(qv[4] * SCALE, Wreg[c * 8 + 4], p0);
        p1 = fmaf(qv[5] * SCALE, Wreg[c * 8 + 5], p1);
        p2 = fmaf(qv[6] * SCALE, Wreg[c * 8 + 6], p2);
        p3 = fmaf(qv[7] * SCALE, Wreg[c * 8 + 7], p3);
      }
      const float arg = fminf((p0 + p1) + (p2 + p3), ECLAMP);
      qp[lr][mth] = RSQM * __expf(arg) + (RSQM * FEPS);
    }
    __syncthreads();
    // denominator partials: 128 threads, 4 x 64-m segments per row
    if (tid < 128) {
      const int lr = tid & 31, part = tid >> 5;
      float su = 0.f;
#pragma unroll
      for (int i = 0; i < 64; i++) su = fmaf(qp[lr][part * 64 + i], ksl[part * 64 + i], su);
      dpart[lr][part] = su;
    }
    // phase 3 partials: all threads; qp rows read wave-broadcast as float4
    float pacc[32];
#pragma unroll
    for (int lr = 0; lr < 32; lr++) {
      const float4* qr = (const float4*)(&qp[lr][mg * 32]);
      float a0 = 0.f, a1 = 0.f, a2 = 0.f, a3 = 0.f;
#pragma unroll
      for (int c = 0; c < 8; c++) {
        float4 qv = qr[c];
        a0 = fmaf(qv.x, kvreg[4 * c + 0], a0);
        a1 = fmaf(qv.y, kvreg[4 * c + 1], a1);
        a2 = fmaf(qv.z, kvreg[4 * c + 2], a2);
        a3 = fmaf(qv.w, kvreg[4 * c + 3], a3);
      }
      pacc[lr] = (a0 + a1) + (a2 + a3);
    }
    __syncthreads();
    if (tid < 32) {
      float d = ((dpart[tid][0] + dpart[tid][1]) + (dpart[tid][2] + dpart[tid][3]));
      if (fabsf(d) <= FEPS) d += 2.0f * FEPS;
      dinv[tid] = 1.0f / d;
    }
    // serial reduce over the 8 m-chunks (column writes are conflict-free)
    for (int g = 0; g < 8; g++) {
      if (mg == g) {
        if (g == 0) {
#pragma unroll
          for (int lr = 0; lr < 32; lr++) accs[lr][dj] = pacc[lr];
        } else {
#pragma unroll
          for (int lr = 0; lr < 32; lr++) accs[lr][dj] += pacc[lr];
        }
      }
      __syncthreads();
    }
    for (int e = tid; e < 32 * 64; e += 512) {
      const int lr = e >> 6, jj = e & 63;
      const int l = s * 32 + lr;
      const float val = accs[lr][jj] * dinv[lr];
      if (MODE == 1)
        ((float*)outp)[tbase + (size_t)l * ND + jj] = val;
      else
        ((u16*)outp)[tbase + (size_t)l * ND + jj] = f2bf(val);
    }
    __syncthreads();
  }
}

extern "C" void kernel_launch(void* const* d_in, const int* in_sizes, int n_in,
                              void* d_out, int out_size, void* d_ws, size_t ws_size,
                              hipStream_t stream) {
  const void* q = d_in[0];
  const void* k = d_in[1];
  const void* v = d_in[2];
  const void* w = d_in[3];

  int* flag = (int*)d_ws;
  float* kvg = (float*)((char*)d_ws + 256);
  float* ksumg = (float*)((char*)d_ws + 256 + (size_t)64 * NM * HDIM * 4);

  detect_kernel<<<1, 256, 0, stream>>>((const u16*)q, flag);
  kv_kernel<0><<<256, 512, 0, stream>>>(k, v, w, flag, kvg, ksumg);
  kv_kernel<1><<<256, 512, 0, stream>>>(k, v, w, flag, kvg, ksumg);
  out_kernel<0><<<4096, 512, 0, stream>>>(q, w, kvg, ksumg, flag, d_out);
  out_kernel<1><<<4096, 512, 0, stream>>>(q, w, kvg, ksumg, flag, d_out);
}

// Round 4
// 1396.338 us; speedup vs baseline: 6.4176x; 6.4176x over previous
//
#include <hip/hip_runtime.h>

// FAVOR+ attention, B=4 L=4096 D=1024 H=16 d=64 m=256. fp32 in/out (confirmed R3).
// stab = 0 (global stabilizer cancels between numerator/denominator; only
// rescales eps — ~1e-6 output effect, verified passing R3).
// K1 kv_kernel, grid 256 = (bh x mc): k' = m^-.5(exp(-.5||k^||^2 + k^.W_m)+eps),
//    kv[m][d] = sum_l k' v, ksum[m] = sum_l k'. Spill-free: Wreg[64]+kvacc[8].
// K2 out_kernel, grid 8192 = (bh x 32-row tile): q' = m^-.5(exp(q^.W_m)+eps),
//    out = (q'@kv) / (q'.ksum). Spill-free: Wreg[64] dies before kvreg[32]+pacc[32].

#define NB 4
#define NL 4096
#define ND 1024
#define NH 16
#define HDIM 64
#define NM 256

#define SCALE 0.17677669529663687f  // 1024^-0.25
#define RSQM 0.0625f                // 256^-0.5
#define FEPS 1e-4f
#define ECLAMP 80.0f                // inert for sane data; bars inf

// Grid: 64 (b,h) x 4 m-chunks = 256 blocks (1/CU), 512 threads = (ml 0..63, lq 0..7).
// Thread owns W row m = mc*64+ml (64 VGPRs) and kv accumulators for
// (m, d = lq*8 .. lq*8+7) (8 VGPRs). k' tile exchanged via LDS.
__global__ __launch_bounds__(512, 2) void kv_kernel(const float* __restrict__ kptr,
                                                    const float* __restrict__ vptr,
                                                    const float* __restrict__ wptr,
                                                    float* __restrict__ kvg,
                                                    float* __restrict__ ksumg) {
  const int bh = blockIdx.x >> 2, mc = blockIdx.x & 3;
  const int b = bh >> 4, h = bh & 15;
  const int tid = threadIdx.x, ml = tid & 63, lq = tid >> 6;

  __shared__ __align__(16) float Kl[32][68];   // scaled K tile
  __shared__ __align__(16) float Vl[32][68];
  __shared__ __align__(16) float kpl[32][68];  // k' tile
  __shared__ float cl[32];
  __shared__ float ksred[8][65];

  float Wreg[64];
  {
    const float4* wr = (const float4*)(wptr + (size_t)(mc * 64 + ml) * HDIM);
#pragma unroll
    for (int c = 0; c < 16; c++) {
      float4 wv = wr[c];
      Wreg[4 * c + 0] = wv.x; Wreg[4 * c + 1] = wv.y;
      Wreg[4 * c + 2] = wv.z; Wreg[4 * c + 3] = wv.w;
    }
  }
  float kvacc[8];
#pragma unroll
  for (int j = 0; j < 8; j++) kvacc[j] = 0.f;
  float ksacc = 0.f;

  const int srow = tid >> 4, scol = (tid & 15) * 4;  // staging map: 32x16 float4
  const size_t gbase = (size_t)b * NL * ND + (size_t)h * HDIM + (size_t)srow * ND + scol;

  for (int t = 0; t < 128; t++) {
    __syncthreads();  // protect LDS from previous iteration's readers
    {
      float4 kv4 = *(const float4*)(kptr + gbase + (size_t)t * 32 * ND);
      float4 vv4 = *(const float4*)(vptr + gbase + (size_t)t * 32 * ND);
      Kl[srow][scol + 0] = kv4.x * SCALE; Kl[srow][scol + 1] = kv4.y * SCALE;
      Kl[srow][scol + 2] = kv4.z * SCALE; Kl[srow][scol + 3] = kv4.w * SCALE;
      *(float4*)(&Vl[srow][scol]) = vv4;
    }
    __syncthreads();
    if (tid < 32) {  // h_l = -0.5||k^||^2 per row (stab = 0)
      const float4* kr = (const float4*)(&Kl[tid][0]);
      float s = 0.f;
#pragma unroll
      for (int c = 0; c < 16; c++) {
        float4 kq = kr[c];
        s = fmaf(kq.x, kq.x, s); s = fmaf(kq.y, kq.y, s);
        s = fmaf(kq.z, kq.z, s); s = fmaf(kq.w, kq.w, s);
      }
      cl[tid] = -0.5f * s;
    }
    __syncthreads();
    // Phase A: k' for rows lq*4..lq*4+3, column ml (K rows broadcast from LDS)
#pragma unroll
    for (int r = 0; r < 4; r++) {
      const int l = lq * 4 + r;
      const float4* kr = (const float4*)(&Kl[l][0]);
      float p0 = 0.f, p1 = 0.f, p2 = 0.f, p3 = 0.f;
#pragma unroll
      for (int c = 0; c < 16; c++) {
        float4 kq = kr[c];
        p0 = fmaf(kq.x, Wreg[4 * c + 0], p0);
        p1 = fmaf(kq.y, Wreg[4 * c + 1], p1);
        p2 = fmaf(kq.z, Wreg[4 * c + 2], p2);
        p3 = fmaf(kq.w, Wreg[4 * c + 3], p3);
      }
      const float arg = fminf(cl[l] + ((p0 + p1) + (p2 + p3)), ECLAMP);
      const float kpv = RSQM * __expf(arg) + (RSQM * FEPS);
      kpl[l][ml] = kpv;
      ksacc += kpv;
    }
    __syncthreads();
    // Phase B: kvacc[j] += sum_l kp[l][ml] * V[l][lq*8+j]
#pragma unroll 4
    for (int l = 0; l < 32; l++) {
      const float kpv = kpl[l][ml];
      const float4 v0 = *(const float4*)(&Vl[l][lq * 8]);
      const float4 v1 = *(const float4*)(&Vl[l][lq * 8 + 4]);
      kvacc[0] = fmaf(kpv, v0.x, kvacc[0]); kvacc[1] = fmaf(kpv, v0.y, kvacc[1]);
      kvacc[2] = fmaf(kpv, v0.z, kvacc[2]); kvacc[3] = fmaf(kpv, v0.w, kvacc[3]);
      kvacc[4] = fmaf(kpv, v1.x, kvacc[4]); kvacc[5] = fmaf(kpv, v1.y, kvacc[5]);
      kvacc[6] = fmaf(kpv, v1.z, kvacc[6]); kvacc[7] = fmaf(kpv, v1.w, kvacc[7]);
    }
  }
  // stores: kv[m][d] block and ksum
  {
    float* dst = kvg + (size_t)bh * NM * HDIM + (size_t)(mc * 64 + ml) * HDIM + lq * 8;
    *(float4*)dst = make_float4(kvacc[0], kvacc[1], kvacc[2], kvacc[3]);
    *(float4*)(dst + 4) = make_float4(kvacc[4], kvacc[5], kvacc[6], kvacc[7]);
  }
  ksred[lq][ml] = ksacc;
  __syncthreads();
  if (tid < 64) {
    float s = 0.f;
#pragma unroll
    for (int g = 0; g < 8; g++) s += ksred[g][tid];
    ksumg[(size_t)bh * NM + mc * 64 + tid] = s;
  }
}

// Grid: 64 (b,h) x 128 L-tiles (32 rows) = 8192 blocks, 512 threads.
// Phase 1 (Wreg live): qp[32][256] in LDS. Phase 2 (Wreg dead): kvreg[32]+pacc[32].
__global__ __launch_bounds__(512, 2) void out_kernel(const float* __restrict__ qptr,
                                                     const float* __restrict__ wptr,
                                                     const float* __restrict__ kvg,
                                                     const float* __restrict__ ksumg,
                                                     float* __restrict__ outp) {
  const int bh = blockIdx.x >> 7, t = blockIdx.x & 127;
  const int b = bh >> 4, h = bh & 15;
  const int tid = threadIdx.x;
  const int mth = tid & 255, hf = tid >> 8;  // phase-1 map
  const int dj = tid & 63, mg = tid >> 6;    // phase-2 map

  __shared__ __align__(16) float Qs[32][68];   // scaled Q tile
  __shared__ __align__(16) float qp[32][260];  // q' tile
  __shared__ float accs[32][64];
  __shared__ float ksl[256];
  __shared__ float dpart[32][8];
  __shared__ float dinv[32];

  float Wreg[64];
  {
    const float4* wr = (const float4*)(wptr + (size_t)mth * HDIM);
#pragma unroll
    for (int c = 0; c < 16; c++) {
      float4 wv = wr[c];
      Wreg[4 * c + 0] = wv.x; Wreg[4 * c + 1] = wv.y;
      Wreg[4 * c + 2] = wv.z; Wreg[4 * c + 3] = wv.w;
    }
  }
  if (tid < 256) ksl[tid] = ksumg[(size_t)bh * NM + tid];
  // stage Q tile (scaled)
  {
    const int srow = tid >> 4, scol = (tid & 15) * 4;
    float4 q4 = *(const float4*)(qptr + (size_t)(b * NL + t * 32 + srow) * ND +
                                 (size_t)h * HDIM + scol);
    Qs[srow][scol + 0] = q4.x * SCALE; Qs[srow][scol + 1] = q4.y * SCALE;
    Qs[srow][scol + 2] = q4.z * SCALE; Qs[srow][scol + 3] = q4.w * SCALE;
  }
  __syncthreads();
  // Phase 1: qp[lr][mth] for 16 rows per thread (Q rows broadcast from LDS)
#pragma unroll
  for (int i = 0; i < 16; i++) {
    const int lr = hf * 16 + i;
    const float4* qr = (const float4*)(&Qs[lr][0]);
    float p0 = 0.f, p1 = 0.f, p2 = 0.f, p3 = 0.f;
#pragma unroll
    for (int c = 0; c < 16; c++) {
      float4 qv = qr[c];
      p0 = fmaf(qv.x, Wreg[4 * c + 0], p0);
      p1 = fmaf(qv.y, Wreg[4 * c + 1], p1);
      p2 = fmaf(qv.z, Wreg[4 * c + 2], p2);
      p3 = fmaf(qv.w, Wreg[4 * c + 3], p3);
    }
    const float arg = fminf((p0 + p1) + (p2 + p3), ECLAMP);
    qp[lr][mth] = RSQM * __expf(arg) + (RSQM * FEPS);
  }
  __syncthreads();  // Wreg dead from here on
  // Phase 2 registers: kv column dj for m-range mg*32..mg*32+31
  float kvreg[32];
  {
    const float* kvb = kvg + (size_t)bh * NM * HDIM + dj;
#pragma unroll
    for (int i = 0; i < 32; i++) kvreg[i] = kvb[(size_t)(mg * 32 + i) * HDIM];
  }
  // denominator partials: 256 threads, 8 x 32-m segments per row
  if (tid < 256) {
    const int lr = tid & 31, part = tid >> 5;
    float su = 0.f;
#pragma unroll
    for (int i = 0; i < 32; i++)
      su = fmaf(qp[lr][part * 32 + i], ksl[part * 32 + i], su);
    dpart[lr][part] = su;
  }
  // numerator partials: qp rows broadcast as float4 x register kv column
  float pacc[32];
#pragma unroll
  for (int lr = 0; lr < 32; lr++) {
    const float4* qr = (const float4*)(&qp[lr][mg * 32]);
    float a0 = 0.f, a1 = 0.f, a2 = 0.f, a3 = 0.f;
#pragma unroll
    for (int c = 0; c < 8; c++) {
      float4 qv = qr[c];
      a0 = fmaf(qv.x, kvreg[4 * c + 0], a0);
      a1 = fmaf(qv.y, kvreg[4 * c + 1], a1);
      a2 = fmaf(qv.z, kvreg[4 * c + 2], a2);
      a3 = fmaf(qv.w, kvreg[4 * c + 3], a3);
    }
    pacc[lr] = (a0 + a1) + (a2 + a3);
  }
  __syncthreads();
  if (tid < 32) {
    float d = 0.f;
#pragma unroll
    for (int p = 0; p < 8; p++) d += dpart[tid][p];
    if (fabsf(d) <= FEPS) d += 2.0f * FEPS;
    dinv[tid] = 1.0f / d;
  }
  // serial reduce over the 8 m-chunks (deterministic; column writes conflict-free)
  for (int g = 0; g < 8; g++) {
    if (mg == g) {
      if (g == 0) {
#pragma unroll
        for (int lr = 0; lr < 32; lr++) accs[lr][dj] = pacc[lr];
      } else {
#pragma unroll
        for (int lr = 0; lr < 32; lr++) accs[lr][dj] += pacc[lr];
      }
    }
    __syncthreads();
  }
  const size_t obase = (size_t)(b * NL + t * 32) * ND + (size_t)h * HDIM;
#pragma unroll
  for (int e = tid; e < 32 * 64; e += 512) {
    const int lr = e >> 6, jj = e & 63;
    outp[obase + (size_t)lr * ND + jj] = accs[lr][jj] * dinv[lr];
  }
}

extern "C" void kernel_launch(void* const* d_in, const int* in_sizes, int n_in,
                              void* d_out, int out_size, void* d_ws, size_t ws_size,
                              hipStream_t stream) {
  const float* q = (const float*)d_in[0];
  const float* k = (const float*)d_in[1];
  const float* v = (const float*)d_in[2];
  const float* w = (const float*)d_in[3];
  float* out = (float*)d_out;

  float* kvg = (float*)d_ws;                                      // [64][256][64]
  float* ksumg = (float*)((char*)d_ws + (size_t)64 * NM * HDIM * 4);  // [64][256]

  kv_kernel<<<256, 512, 0, stream>>>(k, v, w, kvg, ksumg);
  out_kernel<<<8192, 512, 0, stream>>>(q, w, kvg, ksumg, out);
}